// Round 1
// baseline (377.551 us; speedup 1.0000x reference)
//
#include <hip/hip_runtime.h>

#define NN 20000
#define NE 320000
#define EP (NE + NN)          // 340000 with self-loops
#define FIN 128
#define HEADS 8
#define HID 32
#define C1 256                // HEADS*HID
#define C2 64

// ---------------- utility ----------------
__global__ void k_zero_int(int* __restrict__ p, int n) {
    int i = blockIdx.x * 256 + threadIdx.x;
    if (i < n) p[i] = 0;
}

// ---------------- fp32 tiled GEMM: C[M,N] = A[M,K] @ B[K,N] ----------------
// block = 256 threads (16x16), tile 64x64, BK=16. Requires N%64==0, K%16==0.
__global__ void k_gemm(const float* __restrict__ A, const float* __restrict__ B,
                       float* __restrict__ C, int M, int N, int K) {
    __shared__ float As[16][65];
    __shared__ float Bs[16][65];
    const int tx = threadIdx.x & 15;
    const int ty = threadIdx.x >> 4;
    const int bm = blockIdx.y * 64;
    const int bn = blockIdx.x * 64;
    float acc[4][4] = {};
    for (int k0 = 0; k0 < K; k0 += 16) {
        for (int i = threadIdx.x; i < 64 * 16; i += 256) {
            int r = i >> 4, c = i & 15;
            int gr = bm + r;
            As[c][r] = (gr < M) ? A[gr * K + k0 + c] : 0.f;
        }
        for (int i = threadIdx.x; i < 16 * 64; i += 256) {
            int r = i >> 6, c = i & 63;
            Bs[r][c] = B[(k0 + r) * N + bn + c];
        }
        __syncthreads();
#pragma unroll
        for (int k = 0; k < 16; k++) {
            float a[4], b[4];
#pragma unroll
            for (int i = 0; i < 4; i++) a[i] = As[k][ty * 4 + i];
#pragma unroll
            for (int j = 0; j < 4; j++) b[j] = Bs[k][tx * 4 + j];
#pragma unroll
            for (int i = 0; i < 4; i++)
#pragma unroll
                for (int j = 0; j < 4; j++) acc[i][j] += a[i] * b[j];
        }
        __syncthreads();
    }
    for (int i = 0; i < 4; i++) {
        int gr = bm + ty * 4 + i;
        if (gr >= M) continue;
        for (int j = 0; j < 4; j++) C[gr * N + bn + tx * 4 + j] = acc[i][j];
    }
}

// ---------------- layer-1 attention coefficients per node ----------------
// block = 256 (one node): a_s[n,h] = sum_c h1[n,h*32+c]*a_src[h*32+c]
__global__ void k_alpha1(const float* __restrict__ h1, const float* __restrict__ a_src,
                         const float* __restrict__ a_dst, float* __restrict__ as_o,
                         float* __restrict__ ad_o) {
    int n = blockIdx.x, t = threadIdx.x;
    float hv = h1[n * C1 + t];
    float ps = hv * a_src[t];
    float pd = hv * a_dst[t];
    for (int off = 16; off > 0; off >>= 1) {
        ps += __shfl_down(ps, off, 32);
        pd += __shfl_down(pd, off, 32);
    }
    if ((t & 31) == 0) {
        as_o[n * HEADS + (t >> 5)] = ps;
        ad_o[n * HEADS + (t >> 5)] = pd;
    }
}

// ---------------- per-edge exp(leaky_relu(logit)) layer 1 ----------------
__global__ void k_edge1(const int* __restrict__ ei, const float* __restrict__ as,
                        const float* __restrict__ ad, float* __restrict__ e1) {
    int tid = blockIdx.x * 256 + threadIdx.x;
    if (tid >= EP * HEADS) return;
    int e = tid >> 3, h = tid & 7;
    int src, dst;
    if (e < NE) { src = ei[e]; dst = ei[NE + e]; }
    else { src = dst = e - NE; }
    float x = as[src * HEADS + h] + ad[dst * HEADS + h];
    x = (x > 0.f) ? x : 0.2f * x;
    e1[e * HEADS + h] = expf(x);
}

// ---------------- CSR build ----------------
__global__ void k_deg(const int* __restrict__ ei, int* __restrict__ deg) {
    int e = blockIdx.x * 256 + threadIdx.x;
    if (e >= EP) return;
    int dst = (e < NE) ? ei[NE + e] : e - NE;
    atomicAdd(&deg[dst], 1);
}

__global__ __launch_bounds__(1024) void k_scan(const int* __restrict__ deg,
                                               int* __restrict__ rowstart,
                                               int* __restrict__ cursor, int n) {
    __shared__ int sm[1024];
    __shared__ int carry;
    int t = threadIdx.x;
    if (t == 0) carry = 0;
    __syncthreads();
    for (int base = 0; base < n; base += 1024) {
        int v = (base + t < n) ? deg[base + t] : 0;
        sm[t] = v;
        __syncthreads();
        for (int off = 1; off < 1024; off <<= 1) {
            int x = sm[t];
            int y = (t >= off) ? sm[t - off] : 0;
            __syncthreads();
            sm[t] = x + y;
            __syncthreads();
        }
        int excl = sm[t] - v;
        int rs = carry + excl;
        if (base + t < n) { rowstart[base + t] = rs; cursor[base + t] = rs; }
        __syncthreads();
        if (t == 0) carry += sm[1023];
        __syncthreads();
    }
    if (t == 0) rowstart[n] = carry;
}

__global__ void k_scatter(const int* __restrict__ ei, int* __restrict__ cursor,
                          int* __restrict__ csr_src, int* __restrict__ csr_eid) {
    int e = blockIdx.x * 256 + threadIdx.x;
    if (e >= EP) return;
    int src, dst;
    if (e < NE) { src = ei[e]; dst = ei[NE + e]; }
    else { src = dst = e - NE; }
    int pos = atomicAdd(&cursor[dst], 1);
    csr_src[pos] = src;
    csr_eid[pos] = e;
}

// ---------------- layer-1 aggregation (pull), + b1, leaky_relu(0.01) ----------------
// block = 256 (one node, channel per thread)
__global__ void k_agg1(const float* __restrict__ h1, const float* __restrict__ e1,
                       const int* __restrict__ rowstart, const int* __restrict__ csr_src,
                       const int* __restrict__ csr_eid, const float* __restrict__ b1,
                       float* __restrict__ out) {
    int n = blockIdx.x, t = threadIdx.x;
    int h = t >> 5;
    int r0 = rowstart[n], r1 = rowstart[n + 1];
    float s = 0.f;
    for (int j = r0; j < r1; j++) s += e1[csr_eid[j] * HEADS + h];
    float inv = 1.f / (s + 1e-16f);
    float acc = 0.f;
    for (int j = r0; j < r1; j++) {
        float w = e1[csr_eid[j] * HEADS + h] * inv;
        acc += h1[csr_src[j] * C1 + t] * w;
    }
    float v = acc + b1[t];
    out[n * C1 + t] = (v > 0.f) ? v : 0.01f * v;
}

// ---------------- layer-2 attention coefficients ----------------
__global__ void k_alpha2(const float* __restrict__ h2, const float* __restrict__ a_src,
                         const float* __restrict__ a_dst, float* __restrict__ as_o,
                         float* __restrict__ ad_o) {
    int n = blockIdx.x, t = threadIdx.x;  // 64 threads
    float hv = h2[n * C2 + t];
    float ps = hv * a_src[t];
    float pd = hv * a_dst[t];
    for (int off = 32; off > 0; off >>= 1) {
        ps += __shfl_down(ps, off, 64);
        pd += __shfl_down(pd, off, 64);
    }
    if (t == 0) { as_o[n] = ps; ad_o[n] = pd; }
}

__global__ void k_edge2(const int* __restrict__ ei, const float* __restrict__ as,
                        const float* __restrict__ ad, float* __restrict__ e2) {
    int e = blockIdx.x * 256 + threadIdx.x;
    if (e >= EP) return;
    int src, dst;
    if (e < NE) { src = ei[e]; dst = ei[NE + e]; }
    else { src = dst = e - NE; }
    float x = as[src] + ad[dst];
    x = (x > 0.f) ? x : 0.2f * x;
    e2[e] = expf(x);
}

// ---------------- layer-2 aggregation (pull), + b2 ----------------
__global__ void k_agg2(const float* __restrict__ h2, const float* __restrict__ e2,
                       const int* __restrict__ rowstart, const int* __restrict__ csr_src,
                       const int* __restrict__ csr_eid, const float* __restrict__ b2,
                       float* __restrict__ out) {
    int n = blockIdx.x, t = threadIdx.x;  // 64 threads
    int r0 = rowstart[n], r1 = rowstart[n + 1];
    float s = 0.f;
    for (int j = r0; j < r1; j++) s += e2[csr_eid[j]];
    float inv = 1.f / (s + 1e-16f);
    float acc = 0.f;
    for (int j = r0; j < r1; j++) acc += h2[csr_src[j] * C2 + t] * e2[csr_eid[j]] * inv;
    out[n * C2 + t] = acc + b2[t];
}

extern "C" void kernel_launch(void* const* d_in, const int* in_sizes, int n_in,
                              void* d_out, int out_size, void* d_ws, size_t ws_size,
                              hipStream_t stream) {
    const float* x      = (const float*)d_in[0];
    const float* W1     = (const float*)d_in[1];
    const float* a_src1 = (const float*)d_in[2];
    const float* a_dst1 = (const float*)d_in[3];
    const float* b1     = (const float*)d_in[4];
    const float* W2     = (const float*)d_in[5];
    const float* a_src2 = (const float*)d_in[6];
    const float* a_dst2 = (const float*)d_in[7];
    const float* b2     = (const float*)d_in[8];
    const int*   ei     = (const int*)d_in[9];
    float* out = (float*)d_out;

    char* ws = (char*)d_ws;
    size_t off = 0;
    auto alloc = [&](size_t bytes) {
        void* p = ws + off;
        off += (bytes + 255) & ~(size_t)255;
        return p;
    };
    float* h1    = (float*)alloc((size_t)NN * C1 * 4);
    float* hl2   = (float*)alloc((size_t)NN * C1 * 4);
    float* e1    = (float*)alloc((size_t)EP * HEADS * 4);
    float* h2    = (float*)alloc((size_t)NN * C2 * 4);
    float* as1   = (float*)alloc((size_t)NN * HEADS * 4);
    float* ad1   = (float*)alloc((size_t)NN * HEADS * 4);
    float* as2   = (float*)alloc((size_t)NN * 4);
    float* ad2   = (float*)alloc((size_t)NN * 4);
    float* e2    = (float*)alloc((size_t)EP * 4);
    int* deg     = (int*)alloc((size_t)NN * 4);
    int* rowstart= (int*)alloc((size_t)(NN + 1) * 4);
    int* cursor  = (int*)alloc((size_t)NN * 4);
    int* csr_src = (int*)alloc((size_t)EP * 4);
    int* csr_eid = (int*)alloc((size_t)EP * 4);

    const int EB = (EP + 255) / 256;  // edge-parallel blocks

    // CSR build (graph is shared by both layers)
    k_zero_int<<<(NN + 255) / 256, 256, 0, stream>>>(deg, NN);
    k_deg<<<EB, 256, 0, stream>>>(ei, deg);
    k_scan<<<1, 1024, 0, stream>>>(deg, rowstart, cursor, NN);
    k_scatter<<<EB, 256, 0, stream>>>(ei, cursor, csr_src, csr_eid);

    // layer 1
    k_gemm<<<dim3(C1 / 64, (NN + 63) / 64), 256, 0, stream>>>(x, W1, h1, NN, C1, FIN);
    k_alpha1<<<NN, 256, 0, stream>>>(h1, a_src1, a_dst1, as1, ad1);
    k_edge1<<<(EP * HEADS + 255) / 256, 256, 0, stream>>>(ei, as1, ad1, e1);
    k_agg1<<<NN, 256, 0, stream>>>(h1, e1, rowstart, csr_src, csr_eid, b1, hl2);

    // layer 2
    k_gemm<<<dim3(C2 / 64, (NN + 63) / 64), 256, 0, stream>>>(hl2, W2, h2, NN, C2, C1);
    k_alpha2<<<NN, 64, 0, stream>>>(h2, a_src2, a_dst2, as2, ad2);
    k_edge2<<<EB, 256, 0, stream>>>(ei, as2, ad2, e2);
    k_agg2<<<NN, 64, 0, stream>>>(h2, e2, rowstart, csr_src, csr_eid, b2, out);
}

// Round 2
// 289.485 us; speedup vs baseline: 1.3042x; 1.3042x over previous
//
#include <hip/hip_runtime.h>
#include <hip/hip_fp16.h>

#define NN 20000
#define NE 320000
#define EP (NE + NN)          // 340000 with self-loops
#define FIN 128
#define HEADS 8
#define HID 32
#define C1 256                // HEADS*HID
#define C2 64

// ---------------- utility: zero a word region ----------------
__global__ void k_zero(int* __restrict__ p, int n) {
    int i = blockIdx.x * 256 + threadIdx.x;
    if (i < n) p[i] = 0;
}

// ---------------- fp32 tiled GEMM: C[M,N] = A[M,K] @ B[K,N], OT output ----------------
// block = 256 threads (16x16), tile 64x64, BK=16. Requires N%64==0, K%16==0.
template <typename OT>
__global__ void k_gemm(const float* __restrict__ A, const float* __restrict__ B,
                       OT* __restrict__ C, int M, int N, int K) {
    __shared__ float As[16][65];
    __shared__ float Bs[16][65];
    const int tx = threadIdx.x & 15;
    const int ty = threadIdx.x >> 4;
    const int bm = blockIdx.y * 64;
    const int bn = blockIdx.x * 64;
    float acc[4][4] = {};
    for (int k0 = 0; k0 < K; k0 += 16) {
        for (int i = threadIdx.x; i < 64 * 16; i += 256) {
            int r = i >> 4, c = i & 15;
            int gr = bm + r;
            As[c][r] = (gr < M) ? A[(size_t)gr * K + k0 + c] : 0.f;
        }
        for (int i = threadIdx.x; i < 16 * 64; i += 256) {
            int r = i >> 6, c = i & 63;
            Bs[r][c] = B[(size_t)(k0 + r) * N + bn + c];
        }
        __syncthreads();
#pragma unroll
        for (int k = 0; k < 16; k++) {
            float a[4], b[4];
#pragma unroll
            for (int i = 0; i < 4; i++) a[i] = As[k][ty * 4 + i];
#pragma unroll
            for (int j = 0; j < 4; j++) b[j] = Bs[k][tx * 4 + j];
#pragma unroll
            for (int i = 0; i < 4; i++)
#pragma unroll
                for (int j = 0; j < 4; j++) acc[i][j] += a[i] * b[j];
        }
        __syncthreads();
    }
    for (int i = 0; i < 4; i++) {
        int gr = bm + ty * 4 + i;
        if (gr >= M) continue;
        for (int j = 0; j < 4; j++) C[(size_t)gr * N + bn + tx * 4 + j] = (OT)acc[i][j];
    }
}

// ---------------- CSR build ----------------
__global__ void k_deg(const int* __restrict__ ei, int* __restrict__ deg) {
    int e = blockIdx.x * 256 + threadIdx.x;
    if (e >= EP) return;
    int dst = (e < NE) ? ei[NE + e] : e - NE;
    atomicAdd(&deg[dst], 1);
}

__global__ __launch_bounds__(1024) void k_scan(const int* __restrict__ deg,
                                               int* __restrict__ rowstart,
                                               int* __restrict__ cursor, int n) {
    __shared__ int sm[1024];
    __shared__ int carry;
    int t = threadIdx.x;
    if (t == 0) carry = 0;
    __syncthreads();
    for (int base = 0; base < n; base += 1024) {
        int v = (base + t < n) ? deg[base + t] : 0;
        sm[t] = v;
        __syncthreads();
        for (int off = 1; off < 1024; off <<= 1) {
            int x = sm[t];
            int y = (t >= off) ? sm[t - off] : 0;
            __syncthreads();
            sm[t] = x + y;
            __syncthreads();
        }
        int excl = sm[t] - v;
        int rs = carry + excl;
        if (base + t < n) { rowstart[base + t] = rs; cursor[base + t] = rs; }
        __syncthreads();
        if (t == 0) carry += sm[1023];
        __syncthreads();
    }
    if (t == 0) rowstart[n] = carry;
}

__global__ void k_scatter(const int* __restrict__ ei, int* __restrict__ cursor,
                          int* __restrict__ csr_src, int* __restrict__ epos) {
    int e = blockIdx.x * 256 + threadIdx.x;
    if (e >= EP) return;
    int src, dst;
    if (e < NE) { src = ei[e]; dst = ei[NE + e]; }
    else { src = dst = e - NE; }
    int pos = atomicAdd(&cursor[dst], 1);
    csr_src[pos] = src;
    epos[e] = pos;
}

// ---------------- layer-1 attention coefficients (fp16 h, 1 wave/node) ----------------
__global__ void k_alpha1(const __half* __restrict__ h1h, const float* __restrict__ a_src,
                         const float* __restrict__ a_dst, float* __restrict__ as_o,
                         float* __restrict__ ad_o) {
    const int t = threadIdx.x & 63;
    const int n = (blockIdx.x << 2) + (threadIdx.x >> 6);
    float2 q = ((const float2*)(h1h + (size_t)n * C1))[t];
    __half2 p0 = *(__half2*)&q.x, p1 = *(__half2*)&q.y;
    float2 f0 = __half22float2(p0), f1 = __half22float2(p1);
    float4 asv = ((const float4*)a_src)[t];
    float4 adv = ((const float4*)a_dst)[t];
    float ps = f0.x * asv.x + f0.y * asv.y + f1.x * asv.z + f1.y * asv.w;
    float pd = f0.x * adv.x + f0.y * adv.y + f1.x * adv.z + f1.y * adv.w;
    for (int off = 4; off; off >>= 1) {
        ps += __shfl_down(ps, off, 8);
        pd += __shfl_down(pd, off, 8);
    }
    if ((t & 7) == 0) {
        as_o[n * HEADS + (t >> 3)] = ps;
        ad_o[n * HEADS + (t >> 3)] = pd;
    }
}

// ---------------- per-edge exp + CSR-ordered store + atomic denominator (layer 1) ----------------
__global__ void k_edge1(const int* __restrict__ ei, const int* __restrict__ epos,
                        const float* __restrict__ as, const float* __restrict__ ad,
                        float* __restrict__ e1c, float* __restrict__ s1) {
    int tid = blockIdx.x * 256 + threadIdx.x;
    if (tid >= EP * HEADS) return;
    int e = tid >> 3, h = tid & 7;
    int src, dst;
    if (e < NE) { src = ei[e]; dst = ei[NE + e]; }
    else { src = dst = e - NE; }
    float x = as[src * HEADS + h] + ad[dst * HEADS + h];
    x = (x > 0.f) ? x : 0.2f * x;
    float v = expf(x);
    e1c[(size_t)epos[e] * HEADS + h] = v;
    atomicAdd(&s1[dst * HEADS + h], v);
}

// ---------------- layer-1 aggregation: 1 wave/node, fp16 gather, single pass ----------------
__global__ void k_agg1(const __half* __restrict__ h1h, const float* __restrict__ e1c,
                       const float* __restrict__ s1, const int* __restrict__ rowstart,
                       const int* __restrict__ csr_src, const float* __restrict__ b1,
                       float* __restrict__ out) {
    const int t = threadIdx.x & 63;
    const int n = (blockIdx.x << 2) + (threadIdx.x >> 6);
    const int h = t >> 3;  // channels 4t..4t+3 all belong to head t>>3
    const int r0 = rowstart[n], r1 = rowstart[n + 1];
    const float inv = 1.f / (s1[n * HEADS + h] + 1e-16f);
    float a0 = 0.f, a1 = 0.f, a2 = 0.f, a3 = 0.f;
    for (int j = r0; j < r1; ++j) {
        const int src = csr_src[j];
        const float w = e1c[(size_t)j * HEADS + h];
        float2 q = ((const float2*)(h1h + (size_t)src * C1))[t];
        __half2 p0 = *(__half2*)&q.x, p1 = *(__half2*)&q.y;
        float2 f0 = __half22float2(p0), f1 = __half22float2(p1);
        a0 += f0.x * w; a1 += f0.y * w; a2 += f1.x * w; a3 += f1.y * w;
    }
    const float4 bv = ((const float4*)b1)[t];
    float4 o;
    o.x = a0 * inv + bv.x;
    o.y = a1 * inv + bv.y;
    o.z = a2 * inv + bv.z;
    o.w = a3 * inv + bv.w;
    o.x = (o.x > 0.f) ? o.x : 0.01f * o.x;
    o.y = (o.y > 0.f) ? o.y : 0.01f * o.y;
    o.z = (o.z > 0.f) ? o.z : 0.01f * o.z;
    o.w = (o.w > 0.f) ? o.w : 0.01f * o.w;
    ((float4*)(out + (size_t)n * C1))[t] = o;
}

// ---------------- layer-2 attention coefficients (1 wave/node) ----------------
__global__ void k_alpha2(const float* __restrict__ h2, const float* __restrict__ a_src,
                         const float* __restrict__ a_dst, float* __restrict__ as_o,
                         float* __restrict__ ad_o) {
    const int t = threadIdx.x & 63;
    const int n = (blockIdx.x << 2) + (threadIdx.x >> 6);
    float hv = h2[(size_t)n * C2 + t];
    float ps = hv * a_src[t];
    float pd = hv * a_dst[t];
    for (int off = 32; off; off >>= 1) {
        ps += __shfl_down(ps, off, 64);
        pd += __shfl_down(pd, off, 64);
    }
    if (t == 0) { as_o[n] = ps; ad_o[n] = pd; }
}

__global__ void k_edge2(const int* __restrict__ ei, const int* __restrict__ epos,
                        const float* __restrict__ as, const float* __restrict__ ad,
                        float* __restrict__ e2c, float* __restrict__ s2) {
    int e = blockIdx.x * 256 + threadIdx.x;
    if (e >= EP) return;
    int src, dst;
    if (e < NE) { src = ei[e]; dst = ei[NE + e]; }
    else { src = dst = e - NE; }
    float x = as[src] + ad[dst];
    x = (x > 0.f) ? x : 0.2f * x;
    float v = expf(x);
    e2c[epos[e]] = v;
    atomicAdd(&s2[dst], v);
}

// ---------------- layer-2 aggregation: 1 wave/node, single pass ----------------
__global__ void k_agg2(const float* __restrict__ h2, const float* __restrict__ e2c,
                       const float* __restrict__ s2, const int* __restrict__ rowstart,
                       const int* __restrict__ csr_src, const float* __restrict__ b2,
                       float* __restrict__ out) {
    const int t = threadIdx.x & 63;
    const int n = (blockIdx.x << 2) + (threadIdx.x >> 6);
    const int r0 = rowstart[n], r1 = rowstart[n + 1];
    const float inv = 1.f / (s2[n] + 1e-16f);
    float acc = 0.f;
    for (int j = r0; j < r1; ++j) {
        acc += h2[(size_t)csr_src[j] * C2 + t] * e2c[j];
    }
    out[(size_t)n * C2 + t] = acc * inv + b2[t];
}

extern "C" void kernel_launch(void* const* d_in, const int* in_sizes, int n_in,
                              void* d_out, int out_size, void* d_ws, size_t ws_size,
                              hipStream_t stream) {
    const float* x      = (const float*)d_in[0];
    const float* W1     = (const float*)d_in[1];
    const float* a_src1 = (const float*)d_in[2];
    const float* a_dst1 = (const float*)d_in[3];
    const float* b1     = (const float*)d_in[4];
    const float* W2     = (const float*)d_in[5];
    const float* a_src2 = (const float*)d_in[6];
    const float* a_dst2 = (const float*)d_in[7];
    const float* b2     = (const float*)d_in[8];
    const int*   ei     = (const int*)d_in[9];
    float* out = (float*)d_out;

    char* ws = (char*)d_ws;
    size_t off = 0;
    auto alloc = [&](size_t bytes) {
        void* p = ws + off;
        off += (bytes + 255) & ~(size_t)255;
        return p;
    };
    __half* h1h   = (__half*)alloc((size_t)NN * C1 * 2);
    float* hl2    = (float*)alloc((size_t)NN * C1 * 4);
    float* h2     = (float*)alloc((size_t)NN * C2 * 4);
    float* e1c    = (float*)alloc((size_t)EP * HEADS * 4);
    float* e2c    = (float*)alloc((size_t)EP * 4);
    float* as1    = (float*)alloc((size_t)NN * HEADS * 4);
    float* ad1    = (float*)alloc((size_t)NN * HEADS * 4);
    float* as2    = (float*)alloc((size_t)NN * 4);
    float* ad2    = (float*)alloc((size_t)NN * 4);
    // contiguous zero region: deg | s1 | s2
    int*   zbase  = (int*)alloc((size_t)NN * (1 + HEADS + 1) * 4);
    int*   deg    = zbase;
    float* s1     = (float*)(zbase + NN);
    float* s2     = (float*)(zbase + NN + NN * HEADS);
    int* rowstart = (int*)alloc((size_t)(NN + 1) * 4);
    int* cursor   = (int*)alloc((size_t)NN * 4);
    int* csr_src  = (int*)alloc((size_t)EP * 4);
    int* epos     = (int*)alloc((size_t)EP * 4);

    const int EB = (EP + 255) / 256;
    const int ZN = NN * (1 + HEADS + 1);

    // zero deg + s1 + s2
    k_zero<<<(ZN + 255) / 256, 256, 0, stream>>>(zbase, ZN);

    // CSR build (graph shared by both layers)
    k_deg<<<EB, 256, 0, stream>>>(ei, deg);
    k_scan<<<1, 1024, 0, stream>>>(deg, rowstart, cursor, NN);
    k_scatter<<<EB, 256, 0, stream>>>(ei, cursor, csr_src, epos);

    // layer 1
    k_gemm<__half><<<dim3(C1 / 64, (NN + 63) / 64), 256, 0, stream>>>(x, W1, h1h, NN, C1, FIN);
    k_alpha1<<<NN / 4, 256, 0, stream>>>(h1h, a_src1, a_dst1, as1, ad1);
    k_edge1<<<(EP * HEADS + 255) / 256, 256, 0, stream>>>(ei, epos, as1, ad1, e1c, s1);
    k_agg1<<<NN / 4, 256, 0, stream>>>(h1h, e1c, s1, rowstart, csr_src, b1, hl2);

    // layer 2
    k_gemm<float><<<dim3(C2 / 64, (NN + 63) / 64), 256, 0, stream>>>(hl2, W2, h2, NN, C2, C1);
    k_alpha2<<<NN / 4, 256, 0, stream>>>(h2, a_src2, a_dst2, as2, ad2);
    k_edge2<<<EB, 256, 0, stream>>>(ei, epos, as2, ad2, e2c, s2);
    k_agg2<<<NN / 4, 256, 0, stream>>>(h2, e2c, s2, rowstart, csr_src, b2, out);
}

// Round 3
// 222.562 us; speedup vs baseline: 1.6964x; 1.3007x over previous
//
#include <hip/hip_runtime.h>
#include <hip/hip_fp16.h>

#define NN 20000
#define NE 320000
#define EP (NE + NN)          // 340000 with self-loops
#define FIN 128
#define HEADS 8
#define HID 32
#define C1 256                // HEADS*HID
#define C2 64

typedef _Float16 f16;
typedef __attribute__((ext_vector_type(8))) _Float16 f16x8;
typedef __attribute__((ext_vector_type(4))) _Float16 f16x4;
typedef __attribute__((ext_vector_type(4))) float f32x4;

// ---------------- utility: zero a word region ----------------
__global__ void k_zero(int* __restrict__ p, int n) {
    int i = blockIdx.x * 256 + threadIdx.x;
    if (i < n) p[i] = 0;
}

// ---------------- fp32 -> fp16 convert (vectorized) ----------------
__global__ void k_cvt(const float* __restrict__ in, f16* __restrict__ o, int n4) {
    int i = blockIdx.x * 256 + threadIdx.x;
    if (i >= n4) return;
    float4 v = ((const float4*)in)[i];
    f16x4 h = {(_Float16)v.x, (_Float16)v.y, (_Float16)v.z, (_Float16)v.w};
    ((f16x4*)o)[i] = h;
}

// ---------------- W1[128][256],W2[256][64] fp32 -> W1T[256][128],W2T[64][256] fp16 ----------------
__global__ void k_wt(const float* __restrict__ W1, const float* __restrict__ W2,
                     f16* __restrict__ W1T, f16* __restrict__ W2T) {
    int i = blockIdx.x * 256 + threadIdx.x;
    if (i < FIN * C1) {
        int k = i >> 8, n = i & 255;
        W1T[n * FIN + k] = (f16)W1[i];
    } else {
        int j = i - FIN * C1;
        if (j < C1 * C2) {
            int k = j >> 6, n = j & 63;
            W2T[n * C1 + k] = (f16)W2[j];
        }
    }
}

// ---------------- MFMA fp16 GEMM: C[M,N] = A[M,K] @ BT[N,K]^T ----------------
// 64x64 block tile, BK=32, 256 threads = 4 waves, each wave a 32x32 quadrant.
// LDS layout: K-contiguous rows of 64B with XOR swizzle byte ^= (row&7)<<4.
__device__ __forceinline__ int swz(int row, int kb) {
    return (row * 64 + kb) ^ ((row & 7) << 4);
}

template <typename OT>
__global__ __launch_bounds__(256) void k_mgemm(const f16* __restrict__ A,
                                               const f16* __restrict__ BT,
                                               OT* __restrict__ C, int M, int N, int K) {
    __shared__ char lds[8192];
    char* as = lds;
    char* bs = lds + 4096;
    const int t = threadIdx.x;
    const int bm = blockIdx.y * 64;
    const int bn = blockIdx.x * 64;
    const int srow = t >> 2;           // 0..63 staging row
    const int skb = (t & 3) * 16;      // staging byte offset in row
    const int sk8 = (t & 3) * 8;       // staging f16 offset
    const int l = t & 63;
    const int w = t >> 6;
    const int wr = (w >> 1) * 32, wc = (w & 1) * 32;
    const int lr = l & 15, lg = l >> 4;
    f32x4 acc00 = {}, acc01 = {}, acc10 = {}, acc11 = {};
    const bool arow_ok = (bm + srow) < M;
    const f16* gA = A + (size_t)(bm + srow) * K + sk8;
    const f16* gB = BT + (size_t)(bn + srow) * K + sk8;
    for (int k0 = 0; k0 < K; k0 += 32) {
        f16x8 av = {};
        if (arow_ok) av = *(const f16x8*)(gA + k0);
        f16x8 bv = *(const f16x8*)(gB + k0);
        __syncthreads();   // protect previous iteration's fragment reads
        *(f16x8*)(as + swz(srow, skb)) = av;
        *(f16x8*)(bs + swz(srow, skb)) = bv;
        __syncthreads();
        f16x8 a0 = *(f16x8*)(as + swz(wr + lr, lg * 16));
        f16x8 a1 = *(f16x8*)(as + swz(wr + 16 + lr, lg * 16));
        f16x8 b0 = *(f16x8*)(bs + swz(wc + lr, lg * 16));
        f16x8 b1 = *(f16x8*)(bs + swz(wc + 16 + lr, lg * 16));
        acc00 = __builtin_amdgcn_mfma_f32_16x16x32_f16(a0, b0, acc00, 0, 0, 0);
        acc01 = __builtin_amdgcn_mfma_f32_16x16x32_f16(a0, b1, acc01, 0, 0, 0);
        acc10 = __builtin_amdgcn_mfma_f32_16x16x32_f16(a1, b0, acc10, 0, 0, 0);
        acc11 = __builtin_amdgcn_mfma_f32_16x16x32_f16(a1, b1, acc11, 0, 0, 0);
    }
    // C/D layout: col = lane&15, row = (lane>>4)*4 + reg   [m89]
    const int crow0 = bm + wr + lg * 4;
    const int ccol0 = bn + wc + lr;
#pragma unroll
    for (int r = 0; r < 4; ++r) {
        int r0 = crow0 + r;
        if (r0 < M) {
            C[(size_t)r0 * N + ccol0] = (OT)acc00[r];
            C[(size_t)r0 * N + ccol0 + 16] = (OT)acc01[r];
        }
        int r1 = r0 + 16;
        if (r1 < M) {
            C[(size_t)r1 * N + ccol0] = (OT)acc10[r];
            C[(size_t)r1 * N + ccol0 + 16] = (OT)acc11[r];
        }
    }
}

// ---------------- CSR build ----------------
__global__ void k_deg(const int* __restrict__ ei, int* __restrict__ deg) {
    int e = blockIdx.x * 256 + threadIdx.x;
    if (e >= EP) return;
    int dst = (e < NE) ? ei[NE + e] : e - NE;
    atomicAdd(&deg[dst], 1);
}

// 1024 threads, 20 elems/thread serial + wave shuffle scan + cross-wave combine
__global__ __launch_bounds__(1024) void k_scan(const int* __restrict__ deg,
                                               int* __restrict__ rowstart,
                                               int* __restrict__ cursor, int n) {
    const int CH = 20;
    const int t = threadIdx.x;
    const int base = t * CH;
    int v[CH];
    int s = 0;
#pragma unroll
    for (int i = 0; i < CH; ++i) {
        int idx = base + i;
        int d = (idx < n) ? deg[idx] : 0;
        v[i] = s;
        s += d;
    }
    __shared__ int wsum[16];
    const int l = t & 63, w = t >> 6;
    int inc = s;
    for (int off = 1; off < 64; off <<= 1) {
        int y = __shfl_up(inc, off, 64);
        if (l >= off) inc += y;
    }
    if (l == 63) wsum[w] = inc;
    __syncthreads();
    if (w == 0) {
        int ws = (l < 16) ? wsum[l] : 0;
        for (int off = 1; off < 16; off <<= 1) {
            int y = __shfl_up(ws, off, 64);
            if (l >= off) ws += y;
        }
        if (l < 16) wsum[l] = ws;
    }
    __syncthreads();
    const int waveoff = (w == 0) ? 0 : wsum[w - 1];
    const int excl = waveoff + inc - s;
#pragma unroll
    for (int i = 0; i < CH; ++i) {
        int idx = base + i;
        if (idx < n) {
            int rs = excl + v[i];
            rowstart[idx] = rs;
            cursor[idx] = rs;
        }
    }
    if (t == 1023) rowstart[n] = excl + s;
}

__global__ void k_scatter(const int* __restrict__ ei, int* __restrict__ cursor,
                          int* __restrict__ csr_src, int* __restrict__ epos) {
    int e = blockIdx.x * 256 + threadIdx.x;
    if (e >= EP) return;
    int src, dst;
    if (e < NE) { src = ei[e]; dst = ei[NE + e]; }
    else { src = dst = e - NE; }
    int pos = atomicAdd(&cursor[dst], 1);
    csr_src[pos] = src;
    epos[e] = pos;
}

// ---------------- layer-1 attention coefficients (fp16 h, 1 wave/node) ----------------
__global__ void k_alpha1(const f16* __restrict__ h1h, const float* __restrict__ a_src,
                         const float* __restrict__ a_dst, float* __restrict__ as_o,
                         float* __restrict__ ad_o) {
    const int t = threadIdx.x & 63;
    const int n = (blockIdx.x << 2) + (threadIdx.x >> 6);
    f16x4 q = ((const f16x4*)(h1h + (size_t)n * C1))[t];
    float4 asv = ((const float4*)a_src)[t];
    float4 adv = ((const float4*)a_dst)[t];
    float ps = (float)q[0] * asv.x + (float)q[1] * asv.y + (float)q[2] * asv.z + (float)q[3] * asv.w;
    float pd = (float)q[0] * adv.x + (float)q[1] * adv.y + (float)q[2] * adv.z + (float)q[3] * adv.w;
    for (int off = 4; off; off >>= 1) {
        ps += __shfl_down(ps, off, 8);
        pd += __shfl_down(pd, off, 8);
    }
    if ((t & 7) == 0) {
        as_o[n * HEADS + (t >> 3)] = ps;
        ad_o[n * HEADS + (t >> 3)] = pd;
    }
}

// ---------------- per-edge exp + CSR-ordered store + atomic denominator (layer 1) ----------------
__global__ void k_edge1(const int* __restrict__ ei, const int* __restrict__ epos,
                        const float* __restrict__ as, const float* __restrict__ ad,
                        float* __restrict__ e1c, float* __restrict__ s1) {
    int tid = blockIdx.x * 256 + threadIdx.x;
    if (tid >= EP * HEADS) return;
    int e = tid >> 3, h = tid & 7;
    int src, dst;
    if (e < NE) { src = ei[e]; dst = ei[NE + e]; }
    else { src = dst = e - NE; }
    float x = as[src * HEADS + h] + ad[dst * HEADS + h];
    x = (x > 0.f) ? x : 0.2f * x;
    float v = expf(x);
    e1c[(size_t)epos[e] * HEADS + h] = v;
    atomicAdd(&s1[dst * HEADS + h], v);
}

// ---------------- layer-1 aggregation: 1 wave/node, fp16 gather, fp16 out ----------------
__global__ void k_agg1(const f16* __restrict__ h1h, const float* __restrict__ e1c,
                       const float* __restrict__ s1, const int* __restrict__ rowstart,
                       const int* __restrict__ csr_src, const float* __restrict__ b1,
                       f16* __restrict__ out) {
    const int t = threadIdx.x & 63;
    const int n = (blockIdx.x << 2) + (threadIdx.x >> 6);
    const int h = t >> 3;  // channels 4t..4t+3 all belong to head t>>3
    const int r0 = rowstart[n], r1 = rowstart[n + 1];
    const float inv = 1.f / (s1[n * HEADS + h] + 1e-16f);
    float a0 = 0.f, a1 = 0.f, a2 = 0.f, a3 = 0.f;
    for (int j = r0; j < r1; ++j) {
        const int src = csr_src[j];
        const float w = e1c[(size_t)j * HEADS + h];
        f16x4 q = ((const f16x4*)(h1h + (size_t)src * C1))[t];
        a0 += (float)q[0] * w; a1 += (float)q[1] * w;
        a2 += (float)q[2] * w; a3 += (float)q[3] * w;
    }
    const float4 bv = ((const float4*)b1)[t];
    float o0 = a0 * inv + bv.x, o1 = a1 * inv + bv.y;
    float o2 = a2 * inv + bv.z, o3 = a3 * inv + bv.w;
    o0 = (o0 > 0.f) ? o0 : 0.01f * o0;
    o1 = (o1 > 0.f) ? o1 : 0.01f * o1;
    o2 = (o2 > 0.f) ? o2 : 0.01f * o2;
    o3 = (o3 > 0.f) ? o3 : 0.01f * o3;
    f16x4 o16 = {(_Float16)o0, (_Float16)o1, (_Float16)o2, (_Float16)o3};
    ((f16x4*)(out + (size_t)n * C1))[t] = o16;
}

// ---------------- layer-2 attention coefficients (1 wave/node) ----------------
__global__ void k_alpha2(const float* __restrict__ h2, const float* __restrict__ a_src,
                         const float* __restrict__ a_dst, float* __restrict__ as_o,
                         float* __restrict__ ad_o) {
    const int t = threadIdx.x & 63;
    const int n = (blockIdx.x << 2) + (threadIdx.x >> 6);
    float hv = h2[(size_t)n * C2 + t];
    float ps = hv * a_src[t];
    float pd = hv * a_dst[t];
    for (int off = 32; off; off >>= 1) {
        ps += __shfl_down(ps, off, 64);
        pd += __shfl_down(pd, off, 64);
    }
    if (t == 0) { as_o[n] = ps; ad_o[n] = pd; }
}

__global__ void k_edge2(const int* __restrict__ ei, const int* __restrict__ epos,
                        const float* __restrict__ as, const float* __restrict__ ad,
                        float* __restrict__ e2c, float* __restrict__ s2) {
    int e = blockIdx.x * 256 + threadIdx.x;
    if (e >= EP) return;
    int src, dst;
    if (e < NE) { src = ei[e]; dst = ei[NE + e]; }
    else { src = dst = e - NE; }
    float x = as[src] + ad[dst];
    x = (x > 0.f) ? x : 0.2f * x;
    float v = expf(x);
    e2c[epos[e]] = v;
    atomicAdd(&s2[dst], v);
}

// ---------------- layer-2 aggregation: 1 wave/node, single pass ----------------
__global__ void k_agg2(const float* __restrict__ h2, const float* __restrict__ e2c,
                       const float* __restrict__ s2, const int* __restrict__ rowstart,
                       const int* __restrict__ csr_src, const float* __restrict__ b2,
                       float* __restrict__ out) {
    const int t = threadIdx.x & 63;
    const int n = (blockIdx.x << 2) + (threadIdx.x >> 6);
    const int r0 = rowstart[n], r1 = rowstart[n + 1];
    const float inv = 1.f / (s2[n] + 1e-16f);
    float acc = 0.f;
    for (int j = r0; j < r1; ++j) {
        acc += h2[(size_t)csr_src[j] * C2 + t] * e2c[j];
    }
    out[(size_t)n * C2 + t] = acc * inv + b2[t];
}

extern "C" void kernel_launch(void* const* d_in, const int* in_sizes, int n_in,
                              void* d_out, int out_size, void* d_ws, size_t ws_size,
                              hipStream_t stream) {
    const float* x      = (const float*)d_in[0];
    const float* W1     = (const float*)d_in[1];
    const float* a_src1 = (const float*)d_in[2];
    const float* a_dst1 = (const float*)d_in[3];
    const float* b1     = (const float*)d_in[4];
    const float* W2     = (const float*)d_in[5];
    const float* a_src2 = (const float*)d_in[6];
    const float* a_dst2 = (const float*)d_in[7];
    const float* b2     = (const float*)d_in[8];
    const int*   ei     = (const int*)d_in[9];
    float* out = (float*)d_out;

    char* ws = (char*)d_ws;
    size_t off = 0;
    auto alloc = [&](size_t bytes) {
        void* p = ws + off;
        off += (bytes + 255) & ~(size_t)255;
        return p;
    };
    f16*  x16    = (f16*)alloc((size_t)NN * FIN * 2);
    f16*  W1T    = (f16*)alloc((size_t)C1 * FIN * 2);
    f16*  W2T    = (f16*)alloc((size_t)C2 * C1 * 2);
    f16*  h1h    = (f16*)alloc((size_t)NN * C1 * 2);
    f16*  hl2h   = (f16*)alloc((size_t)NN * C1 * 2);
    float* h2    = (float*)alloc((size_t)NN * C2 * 4);
    float* e1c   = (float*)alloc((size_t)EP * HEADS * 4);
    float* e2c   = (float*)alloc((size_t)EP * 4);
    float* as1   = (float*)alloc((size_t)NN * HEADS * 4);
    float* ad1   = (float*)alloc((size_t)NN * HEADS * 4);
    float* as2   = (float*)alloc((size_t)NN * 4);
    float* ad2   = (float*)alloc((size_t)NN * 4);
    // contiguous zero region: deg | s1 | s2
    int*   zbase = (int*)alloc((size_t)NN * (1 + HEADS + 1) * 4);
    int*   deg   = zbase;
    float* s1    = (float*)(zbase + NN);
    float* s2    = (float*)(zbase + NN + NN * HEADS);
    int* rowstart = (int*)alloc((size_t)(NN + 1) * 4);
    int* cursor   = (int*)alloc((size_t)NN * 4);
    int* csr_src  = (int*)alloc((size_t)EP * 4);
    int* epos     = (int*)alloc((size_t)EP * 4);

    const int EB = (EP + 255) / 256;
    const int ZN = NN * (1 + HEADS + 1);

    // zero deg + s1 + s2
    k_zero<<<(ZN + 255) / 256, 256, 0, stream>>>(zbase, ZN);

    // input conversions (independent of CSR)
    k_cvt<<<(NN * FIN / 4 + 255) / 256, 256, 0, stream>>>(x, x16, NN * FIN / 4);
    k_wt<<<(FIN * C1 + C1 * C2 + 255) / 256, 256, 0, stream>>>(W1, W2, W1T, W2T);

    // CSR build (graph shared by both layers)
    k_deg<<<EB, 256, 0, stream>>>(ei, deg);
    k_scan<<<1, 1024, 0, stream>>>(deg, rowstart, cursor, NN);
    k_scatter<<<EB, 256, 0, stream>>>(ei, cursor, csr_src, epos);

    // layer 1
    k_mgemm<f16><<<dim3(C1 / 64, (NN + 63) / 64), 256, 0, stream>>>(x16, W1T, h1h, NN, C1, FIN);
    k_alpha1<<<NN / 4, 256, 0, stream>>>(h1h, a_src1, a_dst1, as1, ad1);
    k_edge1<<<(EP * HEADS + 255) / 256, 256, 0, stream>>>(ei, epos, as1, ad1, e1c, s1);
    k_agg1<<<NN / 4, 256, 0, stream>>>(h1h, e1c, s1, rowstart, csr_src, b1, hl2h);

    // layer 2
    k_mgemm<float><<<dim3(C2 / 64, (NN + 63) / 64), 256, 0, stream>>>(hl2h, W2T, h2, NN, C2, C1);
    k_alpha2<<<NN / 4, 256, 0, stream>>>(h2, a_src2, a_dst2, as2, ad2);
    k_edge2<<<EB, 256, 0, stream>>>(ei, epos, as2, ad2, e2c, s2);
    k_agg2<<<NN / 4, 256, 0, stream>>>(h2, e2c, s2, rowstart, csr_src, b2, out);
}

// Round 4
// 156.708 us; speedup vs baseline: 2.4093x; 1.4202x over previous
//
#include <hip/hip_runtime.h>
#include <hip/hip_fp16.h>

#define NN 20000
#define NE 320000
#define EP (NE + NN)          // 340000 with self-loops
#define FIN 128
#define HEADS 8
#define HID 32
#define C1 256                // HEADS*HID
#define C2 64

typedef _Float16 f16;
typedef __attribute__((ext_vector_type(8))) _Float16 f16x8;
typedef __attribute__((ext_vector_type(4))) _Float16 f16x4;
typedef __attribute__((ext_vector_type(4))) float f32x4;

// ---------------- utility: zero a word region ----------------
__global__ void k_zero(int* __restrict__ p, int n) {
    int i = blockIdx.x * 256 + threadIdx.x;
    if (i < n) p[i] = 0;
}

// ---------------- fp32 -> fp16 convert (vectorized) ----------------
__global__ void k_cvt(const float* __restrict__ in, f16* __restrict__ o, int n4) {
    int i = blockIdx.x * 256 + threadIdx.x;
    if (i >= n4) return;
    float4 v = ((const float4*)in)[i];
    f16x4 h = {(_Float16)v.x, (_Float16)v.y, (_Float16)v.z, (_Float16)v.w};
    ((f16x4*)o)[i] = h;
}

// ---------------- W1[128][256],W2[256][64] fp32 -> W1T[256][128],W2T[64][256] fp16 ----------------
__global__ void k_wt(const float* __restrict__ W1, const float* __restrict__ W2,
                     f16* __restrict__ W1T, f16* __restrict__ W2T) {
    int i = blockIdx.x * 256 + threadIdx.x;
    if (i < FIN * C1) {
        int k = i >> 8, n = i & 255;
        W1T[n * FIN + k] = (f16)W1[i];
    } else {
        int j = i - FIN * C1;
        if (j < C1 * C2) {
            int k = j >> 6, n = j & 63;
            W2T[n * C1 + k] = (f16)W2[j];
        }
    }
}

// ---------------- MFMA fp16 GEMM: C[M,N] = A[M,K] @ BT[N,K]^T ----------------
// 64x64 block tile, BK=32, 256 threads = 4 waves, each wave a 32x32 quadrant.
// LDS layout: K-contiguous rows of 64B with XOR swizzle byte ^= (row&7)<<4.
__device__ __forceinline__ int swz(int row, int kb) {
    return (row * 64 + kb) ^ ((row & 7) << 4);
}

template <typename OT>
__global__ __launch_bounds__(256) void k_mgemm(const f16* __restrict__ A,
                                               const f16* __restrict__ BT,
                                               OT* __restrict__ C, int M, int N, int K) {
    __shared__ char lds[8192];
    char* as = lds;
    char* bs = lds + 4096;
    const int t = threadIdx.x;
    const int bm = blockIdx.y * 64;
    const int bn = blockIdx.x * 64;
    const int srow = t >> 2;           // 0..63 staging row
    const int skb = (t & 3) * 16;      // staging byte offset in row
    const int sk8 = (t & 3) * 8;       // staging f16 offset
    const int l = t & 63;
    const int w = t >> 6;
    const int wr = (w >> 1) * 32, wc = (w & 1) * 32;
    const int lr = l & 15, lg = l >> 4;
    f32x4 acc00 = {}, acc01 = {}, acc10 = {}, acc11 = {};
    const bool arow_ok = (bm + srow) < M;
    const f16* gA = A + (size_t)(bm + srow) * K + sk8;
    const f16* gB = BT + (size_t)(bn + srow) * K + sk8;
    for (int k0 = 0; k0 < K; k0 += 32) {
        f16x8 av = {};
        if (arow_ok) av = *(const f16x8*)(gA + k0);
        f16x8 bv = *(const f16x8*)(gB + k0);
        __syncthreads();   // protect previous iteration's fragment reads
        *(f16x8*)(as + swz(srow, skb)) = av;
        *(f16x8*)(bs + swz(srow, skb)) = bv;
        __syncthreads();
        f16x8 a0 = *(f16x8*)(as + swz(wr + lr, lg * 16));
        f16x8 a1 = *(f16x8*)(as + swz(wr + 16 + lr, lg * 16));
        f16x8 b0 = *(f16x8*)(bs + swz(wc + lr, lg * 16));
        f16x8 b1 = *(f16x8*)(bs + swz(wc + 16 + lr, lg * 16));
        acc00 = __builtin_amdgcn_mfma_f32_16x16x32_f16(a0, b0, acc00, 0, 0, 0);
        acc01 = __builtin_amdgcn_mfma_f32_16x16x32_f16(a0, b1, acc01, 0, 0, 0);
        acc10 = __builtin_amdgcn_mfma_f32_16x16x32_f16(a1, b0, acc10, 0, 0, 0);
        acc11 = __builtin_amdgcn_mfma_f32_16x16x32_f16(a1, b1, acc11, 0, 0, 0);
    }
    // C/D layout: col = lane&15, row = (lane>>4)*4 + reg   [m89]
    const int crow0 = bm + wr + lg * 4;
    const int ccol0 = bn + wc + lr;
#pragma unroll
    for (int r = 0; r < 4; ++r) {
        int r0 = crow0 + r;
        if (r0 < M) {
            C[(size_t)r0 * N + ccol0] = (OT)acc00[r];
            C[(size_t)r0 * N + ccol0 + 16] = (OT)acc01[r];
        }
        int r1 = r0 + 16;
        if (r1 < M) {
            C[(size_t)r1 * N + ccol0] = (OT)acc10[r];
            C[(size_t)r1 * N + ccol0 + 16] = (OT)acc11[r];
        }
    }
}

// ---------------- CSR build ----------------
__global__ void k_deg(const int* __restrict__ ei, int* __restrict__ deg) {
    int e = blockIdx.x * 256 + threadIdx.x;
    if (e >= EP) return;
    int dst = (e < NE) ? ei[NE + e] : e - NE;
    atomicAdd(&deg[dst], 1);
}

// 1024 threads, 20 elems/thread serial + wave shuffle scan + cross-wave combine
__global__ __launch_bounds__(1024) void k_scan(const int* __restrict__ deg,
                                               int* __restrict__ rowstart,
                                               int* __restrict__ cursor, int n) {
    const int CH = 20;
    const int t = threadIdx.x;
    const int base = t * CH;
    int v[CH];
    int s = 0;
#pragma unroll
    for (int i = 0; i < CH; ++i) {
        int idx = base + i;
        int d = (idx < n) ? deg[idx] : 0;
        v[i] = s;
        s += d;
    }
    __shared__ int wsum[16];
    const int l = t & 63, w = t >> 6;
    int inc = s;
    for (int off = 1; off < 64; off <<= 1) {
        int y = __shfl_up(inc, off, 64);
        if (l >= off) inc += y;
    }
    if (l == 63) wsum[w] = inc;
    __syncthreads();
    if (w == 0) {
        int ws = (l < 16) ? wsum[l] : 0;
        for (int off = 1; off < 16; off <<= 1) {
            int y = __shfl_up(ws, off, 64);
            if (l >= off) ws += y;
        }
        if (l < 16) wsum[l] = ws;
    }
    __syncthreads();
    const int waveoff = (w == 0) ? 0 : wsum[w - 1];
    const int excl = waveoff + inc - s;
#pragma unroll
    for (int i = 0; i < CH; ++i) {
        int idx = base + i;
        if (idx < n) {
            int rs = excl + v[i];
            rowstart[idx] = rs;
            cursor[idx] = rs;
        }
    }
    if (t == 1023) rowstart[n] = excl + s;
}

__global__ void k_scatter(const int* __restrict__ ei, int* __restrict__ cursor,
                          int* __restrict__ csr_src, int* __restrict__ csr_dst) {
    int e = blockIdx.x * 256 + threadIdx.x;
    if (e >= EP) return;
    int src, dst;
    if (e < NE) { src = ei[e]; dst = ei[NE + e]; }
    else { src = dst = e - NE; }
    int pos = atomicAdd(&cursor[dst], 1);
    csr_src[pos] = src;
    csr_dst[pos] = dst;
}

// ---------------- layer-1 attention coefficients (fp16 h, 1 wave/node) ----------------
__global__ void k_alpha1(const f16* __restrict__ h1h, const float* __restrict__ a_src,
                         const float* __restrict__ a_dst, float* __restrict__ as_o,
                         float* __restrict__ ad_o) {
    const int t = threadIdx.x & 63;
    const int n = (blockIdx.x << 2) + (threadIdx.x >> 6);
    f16x4 q = ((const f16x4*)(h1h + (size_t)n * C1))[t];
    float4 asv = ((const float4*)a_src)[t];
    float4 adv = ((const float4*)a_dst)[t];
    float ps = (float)q[0] * asv.x + (float)q[1] * asv.y + (float)q[2] * asv.z + (float)q[3] * asv.w;
    float pd = (float)q[0] * adv.x + (float)q[1] * adv.y + (float)q[2] * adv.z + (float)q[3] * adv.w;
    for (int off = 4; off; off >>= 1) {
        ps += __shfl_down(ps, off, 8);
        pd += __shfl_down(pd, off, 8);
    }
    if ((t & 7) == 0) {
        as_o[n * HEADS + (t >> 3)] = ps;
        ad_o[n * HEADS + (t >> 3)] = pd;
    }
}

// ---------------- per-edge exp, CSR(pos)-indexed, layer 1 ----------------
__global__ void k_edge1(const int* __restrict__ csr_src, const int* __restrict__ csr_dst,
                        const float* __restrict__ as, const float* __restrict__ ad,
                        float* __restrict__ e1c) {
    int tid = blockIdx.x * 256 + threadIdx.x;
    if (tid >= EP * HEADS) return;
    int p = tid >> 3, h = tid & 7;
    int src = csr_src[p];
    int dst = csr_dst[p];
    float x = as[src * HEADS + h] + ad[dst * HEADS + h];
    x = (x > 0.f) ? x : 0.2f * x;
    e1c[(size_t)p * HEADS + h] = expf(x);
}

// ---------------- layer-1 aggregation: 1 wave/node, unroll-4 MLP, in-loop denom ----------------
__global__ void k_agg1(const f16* __restrict__ h1h, const float* __restrict__ e1c,
                       const int* __restrict__ rowstart, const int* __restrict__ csr_src,
                       const float* __restrict__ b1, f16* __restrict__ out) {
    const int t = threadIdx.x & 63;
    const int n = (blockIdx.x << 2) + (threadIdx.x >> 6);
    const int h = t >> 3;  // channels 4t..4t+3 all belong to head t>>3
    const int r0 = rowstart[n], r1 = rowstart[n + 1];
    float s = 0.f;
    float a0 = 0.f, a1 = 0.f, a2 = 0.f, a3 = 0.f;
    int j = r0;
    for (; j + 4 <= r1; j += 4) {
        const int s0 = csr_src[j], s1 = csr_src[j + 1];
        const int s2 = csr_src[j + 2], s3 = csr_src[j + 3];
        const float w0 = e1c[(size_t)j * HEADS + h];
        const float w1 = e1c[(size_t)(j + 1) * HEADS + h];
        const float w2 = e1c[(size_t)(j + 2) * HEADS + h];
        const float w3 = e1c[(size_t)(j + 3) * HEADS + h];
        f16x4 q0 = ((const f16x4*)(h1h + (size_t)s0 * C1))[t];
        f16x4 q1 = ((const f16x4*)(h1h + (size_t)s1 * C1))[t];
        f16x4 q2 = ((const f16x4*)(h1h + (size_t)s2 * C1))[t];
        f16x4 q3 = ((const f16x4*)(h1h + (size_t)s3 * C1))[t];
        s += (w0 + w1) + (w2 + w3);
        a0 += (float)q0[0] * w0 + (float)q1[0] * w1 + (float)q2[0] * w2 + (float)q3[0] * w3;
        a1 += (float)q0[1] * w0 + (float)q1[1] * w1 + (float)q2[1] * w2 + (float)q3[1] * w3;
        a2 += (float)q0[2] * w0 + (float)q1[2] * w1 + (float)q2[2] * w2 + (float)q3[2] * w3;
        a3 += (float)q0[3] * w0 + (float)q1[3] * w1 + (float)q2[3] * w2 + (float)q3[3] * w3;
    }
    for (; j < r1; ++j) {
        const int s0 = csr_src[j];
        const float w = e1c[(size_t)j * HEADS + h];
        f16x4 q = ((const f16x4*)(h1h + (size_t)s0 * C1))[t];
        s += w;
        a0 += (float)q[0] * w; a1 += (float)q[1] * w;
        a2 += (float)q[2] * w; a3 += (float)q[3] * w;
    }
    const float inv = 1.f / (s + 1e-16f);
    const float4 bv = ((const float4*)b1)[t];
    float o0 = a0 * inv + bv.x, o1 = a1 * inv + bv.y;
    float o2 = a2 * inv + bv.z, o3 = a3 * inv + bv.w;
    o0 = (o0 > 0.f) ? o0 : 0.01f * o0;
    o1 = (o1 > 0.f) ? o1 : 0.01f * o1;
    o2 = (o2 > 0.f) ? o2 : 0.01f * o2;
    o3 = (o3 > 0.f) ? o3 : 0.01f * o3;
    f16x4 o16 = {(_Float16)o0, (_Float16)o1, (_Float16)o2, (_Float16)o3};
    ((f16x4*)(out + (size_t)n * C1))[t] = o16;
}

// ---------------- layer-2 attention coefficients (1 wave/node) ----------------
__global__ void k_alpha2(const float* __restrict__ h2, const float* __restrict__ a_src,
                         const float* __restrict__ a_dst, float* __restrict__ as_o,
                         float* __restrict__ ad_o) {
    const int t = threadIdx.x & 63;
    const int n = (blockIdx.x << 2) + (threadIdx.x >> 6);
    float hv = h2[(size_t)n * C2 + t];
    float ps = hv * a_src[t];
    float pd = hv * a_dst[t];
    for (int off = 32; off; off >>= 1) {
        ps += __shfl_down(ps, off, 64);
        pd += __shfl_down(pd, off, 64);
    }
    if (t == 0) { as_o[n] = ps; ad_o[n] = pd; }
}

// ---------------- per-edge exp, CSR(pos)-indexed, layer 2 ----------------
__global__ void k_edge2(const int* __restrict__ csr_src, const int* __restrict__ csr_dst,
                        const float* __restrict__ as, const float* __restrict__ ad,
                        float* __restrict__ e2c) {
    int p = blockIdx.x * 256 + threadIdx.x;
    if (p >= EP) return;
    float x = as[csr_src[p]] + ad[csr_dst[p]];
    x = (x > 0.f) ? x : 0.2f * x;
    e2c[p] = expf(x);
}

// ---------------- layer-2 aggregation: 1 wave/node, unroll-4 MLP, in-loop denom ----------------
__global__ void k_agg2(const float* __restrict__ h2, const float* __restrict__ e2c,
                       const int* __restrict__ rowstart, const int* __restrict__ csr_src,
                       const float* __restrict__ b2, float* __restrict__ out) {
    const int t = threadIdx.x & 63;
    const int n = (blockIdx.x << 2) + (threadIdx.x >> 6);
    const int r0 = rowstart[n], r1 = rowstart[n + 1];
    float s = 0.f, acc = 0.f;
    int j = r0;
    for (; j + 4 <= r1; j += 4) {
        const int s0 = csr_src[j], s1 = csr_src[j + 1];
        const int s2 = csr_src[j + 2], s3 = csr_src[j + 3];
        const float w0 = e2c[j], w1 = e2c[j + 1], w2 = e2c[j + 2], w3 = e2c[j + 3];
        const float g0 = h2[(size_t)s0 * C2 + t];
        const float g1 = h2[(size_t)s1 * C2 + t];
        const float g2 = h2[(size_t)s2 * C2 + t];
        const float g3 = h2[(size_t)s3 * C2 + t];
        s += (w0 + w1) + (w2 + w3);
        acc += g0 * w0 + g1 * w1 + g2 * w2 + g3 * w3;
    }
    for (; j < r1; ++j) {
        const float w = e2c[j];
        s += w;
        acc += h2[(size_t)csr_src[j] * C2 + t] * w;
    }
    out[(size_t)n * C2 + t] = acc * (1.f / (s + 1e-16f)) + b2[t];
}

extern "C" void kernel_launch(void* const* d_in, const int* in_sizes, int n_in,
                              void* d_out, int out_size, void* d_ws, size_t ws_size,
                              hipStream_t stream) {
    const float* x      = (const float*)d_in[0];
    const float* W1     = (const float*)d_in[1];
    const float* a_src1 = (const float*)d_in[2];
    const float* a_dst1 = (const float*)d_in[3];
    const float* b1     = (const float*)d_in[4];
    const float* W2     = (const float*)d_in[5];
    const float* a_src2 = (const float*)d_in[6];
    const float* a_dst2 = (const float*)d_in[7];
    const float* b2     = (const float*)d_in[8];
    const int*   ei     = (const int*)d_in[9];
    float* out = (float*)d_out;

    char* ws = (char*)d_ws;
    size_t off = 0;
    auto alloc = [&](size_t bytes) {
        void* p = ws + off;
        off += (bytes + 255) & ~(size_t)255;
        return p;
    };
    f16*  x16    = (f16*)alloc((size_t)NN * FIN * 2);
    f16*  W1T    = (f16*)alloc((size_t)C1 * FIN * 2);
    f16*  W2T    = (f16*)alloc((size_t)C2 * C1 * 2);
    f16*  h1h    = (f16*)alloc((size_t)NN * C1 * 2);
    f16*  hl2h   = (f16*)alloc((size_t)NN * C1 * 2);
    float* h2    = (float*)alloc((size_t)NN * C2 * 4);
    float* e1c   = (float*)alloc((size_t)EP * HEADS * 4);
    float* e2c   = (float*)alloc((size_t)EP * 4);
    float* as1   = (float*)alloc((size_t)NN * HEADS * 4);
    float* ad1   = (float*)alloc((size_t)NN * HEADS * 4);
    float* as2   = (float*)alloc((size_t)NN * 4);
    float* ad2   = (float*)alloc((size_t)NN * 4);
    int*   deg   = (int*)alloc((size_t)NN * 4);
    int* rowstart = (int*)alloc((size_t)(NN + 1) * 4);
    int* cursor   = (int*)alloc((size_t)NN * 4);
    int* csr_src  = (int*)alloc((size_t)EP * 4);
    int* csr_dst  = (int*)alloc((size_t)EP * 4);

    const int EB = (EP + 255) / 256;

    // zero deg
    k_zero<<<(NN + 255) / 256, 256, 0, stream>>>(deg, NN);

    // input conversions (independent of CSR)
    k_cvt<<<(NN * FIN / 4 + 255) / 256, 256, 0, stream>>>(x, x16, NN * FIN / 4);
    k_wt<<<(FIN * C1 + C1 * C2 + 255) / 256, 256, 0, stream>>>(W1, W2, W1T, W2T);

    // CSR build (graph shared by both layers)
    k_deg<<<EB, 256, 0, stream>>>(ei, deg);
    k_scan<<<1, 1024, 0, stream>>>(deg, rowstart, cursor, NN);
    k_scatter<<<EB, 256, 0, stream>>>(ei, cursor, csr_src, csr_dst);

    // layer 1
    k_mgemm<f16><<<dim3(C1 / 64, (NN + 63) / 64), 256, 0, stream>>>(x16, W1T, h1h, NN, C1, FIN);
    k_alpha1<<<NN / 4, 256, 0, stream>>>(h1h, a_src1, a_dst1, as1, ad1);
    k_edge1<<<(EP * HEADS + 255) / 256, 256, 0, stream>>>(csr_src, csr_dst, as1, ad1, e1c);
    k_agg1<<<NN / 4, 256, 0, stream>>>(h1h, e1c, rowstart, csr_src, b1, hl2h);

    // layer 2
    k_mgemm<float><<<dim3(C2 / 64, (NN + 63) / 64), 256, 0, stream>>>(hl2h, W2T, h2, NN, C2, C1);
    k_alpha2<<<NN / 4, 256, 0, stream>>>(h2, a_src2, a_dst2, as2, ad2);
    k_edge2<<<EB, 256, 0, stream>>>(csr_src, csr_dst, as2, ad2, e2c);
    k_agg2<<<NN / 4, 256, 0, stream>>>(h2, e2c, rowstart, csr_src, b2, out);
}

// Round 5
// 139.134 us; speedup vs baseline: 2.7136x; 1.1263x over previous
//
#include <hip/hip_runtime.h>
#include <hip/hip_fp16.h>

#define NN 20000
#define NE 320000
#define EP (NE + NN)          // 340000 with self-loops
#define FIN 128
#define HEADS 8
#define HID 32
#define C1 256                // HEADS*HID
#define C2 64

typedef _Float16 f16;
typedef __attribute__((ext_vector_type(8))) _Float16 f16x8;
typedef __attribute__((ext_vector_type(4))) _Float16 f16x4;
typedef __attribute__((ext_vector_type(4))) float f32x4;

// ---------------- fused prep: x->fp16, W1/W2 transpose->fp16, zero deg ----------------
__global__ void k_prep(const float* __restrict__ x, f16* __restrict__ x16,
                       const float* __restrict__ W1, const float* __restrict__ W2,
                       f16* __restrict__ W1T, f16* __restrict__ W2T,
                       int* __restrict__ deg) {
    int i = blockIdx.x * 256 + threadIdx.x;
    const int NX = NN * FIN / 4;
    if (i < NX) {
        float4 v = ((const float4*)x)[i];
        f16x4 h = {(_Float16)v.x, (_Float16)v.y, (_Float16)v.z, (_Float16)v.w};
        ((f16x4*)x16)[i] = h;
        return;
    }
    int j = i - NX;
    if (j < FIN * C1) {
        int k = j >> 8, n = j & 255;
        W1T[n * FIN + k] = (f16)W1[j];
        return;
    }
    j -= FIN * C1;
    if (j < C1 * C2) {
        int k = j >> 6, n = j & 63;
        W2T[n * C1 + k] = (f16)W2[j];
        return;
    }
    j -= C1 * C2;
    if (j < NN) deg[j] = 0;
}

// ---------------- MFMA fp16 GEMM: C[M,N] = A[M,K] @ BT[N,K]^T ----------------
// 64x64 block tile, BK=32, 256 threads = 4 waves, each wave a 32x32 quadrant.
// LDS layout: K-contiguous rows of 64B with XOR swizzle byte ^= (row&7)<<4.
// DA=true: also emit per-(row,head) dots with a_src/a_dst (alpha1 fusion) --
// each wave quadrant's 32 cols == one head, so a 16-lane shfl reduce suffices.
__device__ __forceinline__ int swz(int row, int kb) {
    return (row * 64 + kb) ^ ((row & 7) << 4);
}

template <typename OT, bool DA>
__global__ __launch_bounds__(256) void k_mgemm(const f16* __restrict__ A,
                                               const f16* __restrict__ BT,
                                               OT* __restrict__ C, int M, int N, int K,
                                               const float* __restrict__ a_src,
                                               const float* __restrict__ a_dst,
                                               float* __restrict__ as_o,
                                               float* __restrict__ ad_o) {
    __shared__ char lds[8192];
    char* as = lds;
    char* bs = lds + 4096;
    const int t = threadIdx.x;
    const int bm = blockIdx.y * 64;
    const int bn = blockIdx.x * 64;
    const int srow = t >> 2;           // 0..63 staging row
    const int skb = (t & 3) * 16;      // staging byte offset in row
    const int sk8 = (t & 3) * 8;       // staging f16 offset
    const int l = t & 63;
    const int w = t >> 6;
    const int wr = (w >> 1) * 32, wc = (w & 1) * 32;
    const int lr = l & 15, lg = l >> 4;
    f32x4 acc00 = {}, acc01 = {}, acc10 = {}, acc11 = {};
    const bool arow_ok = (bm + srow) < M;
    const f16* gA = A + (size_t)(bm + srow) * K + sk8;
    const f16* gB = BT + (size_t)(bn + srow) * K + sk8;
    for (int k0 = 0; k0 < K; k0 += 32) {
        f16x8 av = {};
        if (arow_ok) av = *(const f16x8*)(gA + k0);
        f16x8 bv = *(const f16x8*)(gB + k0);
        __syncthreads();   // protect previous iteration's fragment reads
        *(f16x8*)(as + swz(srow, skb)) = av;
        *(f16x8*)(bs + swz(srow, skb)) = bv;
        __syncthreads();
        f16x8 a0 = *(f16x8*)(as + swz(wr + lr, lg * 16));
        f16x8 a1 = *(f16x8*)(as + swz(wr + 16 + lr, lg * 16));
        f16x8 b0 = *(f16x8*)(bs + swz(wc + lr, lg * 16));
        f16x8 b1 = *(f16x8*)(bs + swz(wc + 16 + lr, lg * 16));
        acc00 = __builtin_amdgcn_mfma_f32_16x16x32_f16(a0, b0, acc00, 0, 0, 0);
        acc01 = __builtin_amdgcn_mfma_f32_16x16x32_f16(a0, b1, acc01, 0, 0, 0);
        acc10 = __builtin_amdgcn_mfma_f32_16x16x32_f16(a1, b0, acc10, 0, 0, 0);
        acc11 = __builtin_amdgcn_mfma_f32_16x16x32_f16(a1, b1, acc11, 0, 0, 0);
    }
    // C/D layout: col = lane&15, row = (lane>>4)*4 + reg   [m89]
    const int crow0 = bm + wr + lg * 4;
    const int ccol0 = bn + wc + lr;
#pragma unroll
    for (int r = 0; r < 4; ++r) {
        int r0 = crow0 + r;
        if (r0 < M) {
            C[(size_t)r0 * N + ccol0] = (OT)acc00[r];
            C[(size_t)r0 * N + ccol0 + 16] = (OT)acc01[r];
        }
        int r1 = r0 + 16;
        if (r1 < M) {
            C[(size_t)r1 * N + ccol0] = (OT)acc10[r];
            C[(size_t)r1 * N + ccol0 + 16] = (OT)acc11[r];
        }
    }
    if constexpr (DA) {
        const float av0 = a_src[ccol0], av1 = a_src[ccol0 + 16];
        const float dv0 = a_dst[ccol0], dv1 = a_dst[ccol0 + 16];
        const int head = (bn + wc) >> 5;
#pragma unroll
        for (int r = 0; r < 4; ++r) {
            float ps0 = acc00[r] * av0 + acc01[r] * av1;
            float pd0 = acc00[r] * dv0 + acc01[r] * dv1;
            float ps1 = acc10[r] * av0 + acc11[r] * av1;
            float pd1 = acc10[r] * dv0 + acc11[r] * dv1;
#pragma unroll
            for (int off = 1; off < 16; off <<= 1) {
                ps0 += __shfl_xor(ps0, off, 16);
                pd0 += __shfl_xor(pd0, off, 16);
                ps1 += __shfl_xor(ps1, off, 16);
                pd1 += __shfl_xor(pd1, off, 16);
            }
            if (lr == 0) {
                int row0 = crow0 + r, row1 = row0 + 16;
                if (row0 < M) { as_o[row0 * HEADS + head] = ps0; ad_o[row0 * HEADS + head] = pd0; }
                if (row1 < M) { as_o[row1 * HEADS + head] = ps1; ad_o[row1 * HEADS + head] = pd1; }
            }
        }
    }
}

// ---------------- CSR build ----------------
__global__ void k_deg(const int* __restrict__ ei, int* __restrict__ deg) {
    int e = blockIdx.x * 256 + threadIdx.x;
    if (e >= EP) return;
    int dst = (e < NE) ? ei[NE + e] : e - NE;
    atomicAdd(&deg[dst], 1);
}

// 1024 threads, 20 elems/thread serial + wave shuffle scan + cross-wave combine
__global__ __launch_bounds__(1024) void k_scan(const int* __restrict__ deg,
                                               int* __restrict__ rowstart,
                                               int* __restrict__ cursor, int n) {
    const int CH = 20;
    const int t = threadIdx.x;
    const int base = t * CH;
    int v[CH];
    int s = 0;
#pragma unroll
    for (int i = 0; i < CH; ++i) {
        int idx = base + i;
        int d = (idx < n) ? deg[idx] : 0;
        v[i] = s;
        s += d;
    }
    __shared__ int wsum[16];
    const int l = t & 63, w = t >> 6;
    int inc = s;
    for (int off = 1; off < 64; off <<= 1) {
        int y = __shfl_up(inc, off, 64);
        if (l >= off) inc += y;
    }
    if (l == 63) wsum[w] = inc;
    __syncthreads();
    if (w == 0) {
        int ws = (l < 16) ? wsum[l] : 0;
        for (int off = 1; off < 16; off <<= 1) {
            int y = __shfl_up(ws, off, 64);
            if (l >= off) ws += y;
        }
        if (l < 16) wsum[l] = ws;
    }
    __syncthreads();
    const int waveoff = (w == 0) ? 0 : wsum[w - 1];
    const int excl = waveoff + inc - s;
#pragma unroll
    for (int i = 0; i < CH; ++i) {
        int idx = base + i;
        if (idx < n) {
            int rs = excl + v[i];
            rowstart[idx] = rs;
            cursor[idx] = rs;
        }
    }
    if (t == 1023) rowstart[n] = excl + s;
}

__global__ void k_scatter(const int* __restrict__ ei, int* __restrict__ cursor,
                          int* __restrict__ csr_src) {
    int e = blockIdx.x * 256 + threadIdx.x;
    if (e >= EP) return;
    int src, dst;
    if (e < NE) { src = ei[e]; dst = ei[NE + e]; }
    else { src = dst = e - NE; }
    int pos = atomicAdd(&cursor[dst], 1);
    csr_src[pos] = src;
}

// ---------------- layer-1 agg, edge-weights computed in-loop ----------------
// 1 wave/node, lane t: head h=t>>3, channels 4t..4t+3. unroll-4 for MLP.
__global__ void k_agg1(const f16* __restrict__ h1h, const float* __restrict__ as1,
                       const float* __restrict__ ad1, const int* __restrict__ rowstart,
                       const int* __restrict__ csr_src, const float* __restrict__ b1,
                       f16* __restrict__ out) {
    const int t = threadIdx.x & 63;
    const int n = (blockIdx.x << 2) + (threadIdx.x >> 6);
    const int h = t >> 3;
    const int r0 = rowstart[n], r1 = rowstart[n + 1];
    const float adn = ad1[n * HEADS + h];
    float s = 0.f;
    float a0 = 0.f, a1 = 0.f, a2 = 0.f, a3 = 0.f;
    int j = r0;
    for (; j + 4 <= r1; j += 4) {
        const int s0 = csr_src[j], s1 = csr_src[j + 1];
        const int s2 = csr_src[j + 2], s3 = csr_src[j + 3];
        float x0 = as1[s0 * HEADS + h] + adn;
        float x1 = as1[s1 * HEADS + h] + adn;
        float x2 = as1[s2 * HEADS + h] + adn;
        float x3 = as1[s3 * HEADS + h] + adn;
        f16x4 q0 = ((const f16x4*)(h1h + (size_t)s0 * C1))[t];
        f16x4 q1 = ((const f16x4*)(h1h + (size_t)s1 * C1))[t];
        f16x4 q2 = ((const f16x4*)(h1h + (size_t)s2 * C1))[t];
        f16x4 q3 = ((const f16x4*)(h1h + (size_t)s3 * C1))[t];
        x0 = (x0 > 0.f) ? x0 : 0.2f * x0;
        x1 = (x1 > 0.f) ? x1 : 0.2f * x1;
        x2 = (x2 > 0.f) ? x2 : 0.2f * x2;
        x3 = (x3 > 0.f) ? x3 : 0.2f * x3;
        const float w0 = expf(x0), w1 = expf(x1), w2 = expf(x2), w3 = expf(x3);
        s += (w0 + w1) + (w2 + w3);
        a0 += (float)q0[0] * w0 + (float)q1[0] * w1 + (float)q2[0] * w2 + (float)q3[0] * w3;
        a1 += (float)q0[1] * w0 + (float)q1[1] * w1 + (float)q2[1] * w2 + (float)q3[1] * w3;
        a2 += (float)q0[2] * w0 + (float)q1[2] * w1 + (float)q2[2] * w2 + (float)q3[2] * w3;
        a3 += (float)q0[3] * w0 + (float)q1[3] * w1 + (float)q2[3] * w2 + (float)q3[3] * w3;
    }
    for (; j < r1; ++j) {
        const int s0 = csr_src[j];
        float x = as1[s0 * HEADS + h] + adn;
        x = (x > 0.f) ? x : 0.2f * x;
        const float w = expf(x);
        f16x4 q = ((const f16x4*)(h1h + (size_t)s0 * C1))[t];
        s += w;
        a0 += (float)q[0] * w; a1 += (float)q[1] * w;
        a2 += (float)q[2] * w; a3 += (float)q[3] * w;
    }
    const float inv = 1.f / (s + 1e-16f);
    const float4 bv = ((const float4*)b1)[t];
    float o0 = a0 * inv + bv.x, o1 = a1 * inv + bv.y;
    float o2 = a2 * inv + bv.z, o3 = a3 * inv + bv.w;
    o0 = (o0 > 0.f) ? o0 : 0.01f * o0;
    o1 = (o1 > 0.f) ? o1 : 0.01f * o1;
    o2 = (o2 > 0.f) ? o2 : 0.01f * o2;
    o3 = (o3 > 0.f) ? o3 : 0.01f * o3;
    f16x4 o16 = {(_Float16)o0, (_Float16)o1, (_Float16)o2, (_Float16)o3};
    ((f16x4*)(out + (size_t)n * C1))[t] = o16;
}

// ---------------- layer-2 attention coefficients (1 wave/node) ----------------
__global__ void k_alpha2(const float* __restrict__ h2, const float* __restrict__ a_src,
                         const float* __restrict__ a_dst, float* __restrict__ as_o,
                         float* __restrict__ ad_o) {
    const int t = threadIdx.x & 63;
    const int n = (blockIdx.x << 2) + (threadIdx.x >> 6);
    float hv = h2[(size_t)n * C2 + t];
    float ps = hv * a_src[t];
    float pd = hv * a_dst[t];
    for (int off = 32; off; off >>= 1) {
        ps += __shfl_down(ps, off, 64);
        pd += __shfl_down(pd, off, 64);
    }
    if (t == 0) { as_o[n] = ps; ad_o[n] = pd; }
}

// ---------------- layer-2 agg, edge-weights in-loop (as2[src] broadcasts) ----------------
__global__ void k_agg2(const float* __restrict__ h2, const float* __restrict__ as2,
                       const float* __restrict__ ad2, const int* __restrict__ rowstart,
                       const int* __restrict__ csr_src, const float* __restrict__ b2,
                       float* __restrict__ out) {
    const int t = threadIdx.x & 63;
    const int n = (blockIdx.x << 2) + (threadIdx.x >> 6);
    const int r0 = rowstart[n], r1 = rowstart[n + 1];
    const float adn = ad2[n];
    float s = 0.f, acc = 0.f;
    int j = r0;
    for (; j + 4 <= r1; j += 4) {
        const int s0 = csr_src[j], s1 = csr_src[j + 1];
        const int s2 = csr_src[j + 2], s3 = csr_src[j + 3];
        float x0 = as2[s0] + adn, x1 = as2[s1] + adn;
        float x2 = as2[s2] + adn, x3 = as2[s3] + adn;
        const float g0 = h2[(size_t)s0 * C2 + t];
        const float g1 = h2[(size_t)s1 * C2 + t];
        const float g2 = h2[(size_t)s2 * C2 + t];
        const float g3 = h2[(size_t)s3 * C2 + t];
        x0 = (x0 > 0.f) ? x0 : 0.2f * x0;
        x1 = (x1 > 0.f) ? x1 : 0.2f * x1;
        x2 = (x2 > 0.f) ? x2 : 0.2f * x2;
        x3 = (x3 > 0.f) ? x3 : 0.2f * x3;
        const float w0 = expf(x0), w1 = expf(x1), w2 = expf(x2), w3 = expf(x3);
        s += (w0 + w1) + (w2 + w3);
        acc += g0 * w0 + g1 * w1 + g2 * w2 + g3 * w3;
    }
    for (; j < r1; ++j) {
        const int s0 = csr_src[j];
        float x = as2[s0] + adn;
        x = (x > 0.f) ? x : 0.2f * x;
        const float w = expf(x);
        s += w;
        acc += h2[(size_t)s0 * C2 + t] * w;
    }
    out[(size_t)n * C2 + t] = acc * (1.f / (s + 1e-16f)) + b2[t];
}

extern "C" void kernel_launch(void* const* d_in, const int* in_sizes, int n_in,
                              void* d_out, int out_size, void* d_ws, size_t ws_size,
                              hipStream_t stream) {
    const float* x      = (const float*)d_in[0];
    const float* W1     = (const float*)d_in[1];
    const float* a_src1 = (const float*)d_in[2];
    const float* a_dst1 = (const float*)d_in[3];
    const float* b1     = (const float*)d_in[4];
    const float* W2     = (const float*)d_in[5];
    const float* a_src2 = (const float*)d_in[6];
    const float* a_dst2 = (const float*)d_in[7];
    const float* b2     = (const float*)d_in[8];
    const int*   ei     = (const int*)d_in[9];
    float* out = (float*)d_out;

    char* ws = (char*)d_ws;
    size_t off = 0;
    auto alloc = [&](size_t bytes) {
        void* p = ws + off;
        off += (bytes + 255) & ~(size_t)255;
        return p;
    };
    f16*  x16    = (f16*)alloc((size_t)NN * FIN * 2);
    f16*  W1T    = (f16*)alloc((size_t)C1 * FIN * 2);
    f16*  W2T    = (f16*)alloc((size_t)C2 * C1 * 2);
    f16*  h1h    = (f16*)alloc((size_t)NN * C1 * 2);
    f16*  hl2h   = (f16*)alloc((size_t)NN * C1 * 2);
    float* h2    = (float*)alloc((size_t)NN * C2 * 4);
    float* as1   = (float*)alloc((size_t)NN * HEADS * 4);
    float* ad1   = (float*)alloc((size_t)NN * HEADS * 4);
    float* as2   = (float*)alloc((size_t)NN * 4);
    float* ad2   = (float*)alloc((size_t)NN * 4);
    int*   deg   = (int*)alloc((size_t)NN * 4);
    int* rowstart = (int*)alloc((size_t)(NN + 1) * 4);
    int* cursor   = (int*)alloc((size_t)NN * 4);
    int* csr_src  = (int*)alloc((size_t)EP * 4);

    const int EB = (EP + 255) / 256;
    const int PREP_N = NN * FIN / 4 + FIN * C1 + C1 * C2 + NN;

    // prep: x->fp16, W transposes, zero deg
    k_prep<<<(PREP_N + 255) / 256, 256, 0, stream>>>(x, x16, W1, W2, W1T, W2T, deg);

    // CSR build (graph shared by both layers)
    k_deg<<<EB, 256, 0, stream>>>(ei, deg);
    k_scan<<<1, 1024, 0, stream>>>(deg, rowstart, cursor, NN);
    k_scatter<<<EB, 256, 0, stream>>>(ei, cursor, csr_src);

    // layer 1 (GEMM fused with alpha1)
    k_mgemm<f16, true><<<dim3(C1 / 64, (NN + 63) / 64), 256, 0, stream>>>(
        x16, W1T, h1h, NN, C1, FIN, a_src1, a_dst1, as1, ad1);
    k_agg1<<<NN / 4, 256, 0, stream>>>(h1h, as1, ad1, rowstart, csr_src, b1, hl2h);

    // layer 2
    k_mgemm<float, false><<<dim3(C2 / 64, (NN + 63) / 64), 256, 0, stream>>>(
        hl2h, W2T, h2, NN, C2, C1, nullptr, nullptr, nullptr, nullptr);
    k_alpha2<<<NN / 4, 256, 0, stream>>>(h2, a_src2, a_dst2, as2, ad2);
    k_agg2<<<NN / 4, 256, 0, stream>>>(h2, as2, ad2, rowstart, csr_src, b2, out);
}